// Round 17
// baseline (92.930 us; speedup 1.0000x reference)
//
#include <hip/hip_runtime.h>
#include <hip/hip_bf16.h>

#define SEQ 14
#define IN 24
#define H 64
#define CLS 10
#define NBATCH 65536
#define NB 32   // batch elems per block (best measured geometry)
// 2*log2(e): folds tanh's 2*v AND exp->exp2 into the f32 weight/bias prescale.
#define WSCALE 2.8853900817779268f

typedef __attribute__((ext_vector_type(4))) float f32x4;
typedef __attribute__((ext_vector_type(8))) short bf16x8;
typedef __attribute__((ext_vector_type(4))) short bf16x4;

#define MFMA(A, B, C) __builtin_amdgcn_mfma_f32_16x16x32_bf16(A, B, C, 0, 0, 0)
// Anti-rematerialization pin (R5-verified).
#define PIN(v) asm volatile("" : "+v"(v))
// Interval barrier: lgkmcnt(0) only (R15/R16-verified safe & neutral; kept
// because it can only help once occupancy rises).
#define BAR()                                                \
    do {                                                     \
        asm volatile("s_waitcnt lgkmcnt(0)" ::: "memory");   \
        __builtin_amdgcn_s_barrier();                        \
    } while (0)

static __device__ __forceinline__ float fexp2(float x) {
#if __has_builtin(__builtin_amdgcn_exp2f)
    return __builtin_amdgcn_exp2f(x);   // v_exp_f32 (2^x)
#else
    return __expf(x * 0.6931471805599453f);
#endif
}
// y = 2*v*log2(e) (prescaled weights): tanh(v) = 1 - 2/(2^y + 1)
static __device__ __forceinline__ float tanh2(float y) {
    float e = fexp2(y);
    return fmaf(-2.0f, __builtin_amdgcn_rcpf(e + 1.0f), 1.0f);
}
static __device__ __forceinline__ short f2bf(float f) {
    __hip_bfloat16 h = __float2bfloat16(f);
    union { __hip_bfloat16 h; short s; } u; u.h = h;
    return u.s;
}
static __device__ __forceinline__ bf16x8 pack8(f32x4 a, f32x4 b) {
    bf16x8 r;
    r[0] = f2bf(a[0]); r[1] = f2bf(a[1]); r[2] = f2bf(a[2]); r[3] = f2bf(a[3]);
    r[4] = f2bf(b[0]); r[5] = f2bf(b[1]); r[6] = f2bf(b[2]); r[7] = f2bf(b[3]);
    return r;
}
static __device__ __forceinline__ bf16x8 loadw8(const float* p) {
    return pack8(*(const f32x4*)p, *(const f32x4*)(p + 4));
}
static __device__ __forceinline__ bf16x8 loadw8s(const float* p, float s) {
    f32x4 a = *(const f32x4*)p, b = *(const f32x4*)(p + 4);
    return pack8(a * s, b * s);
}

// R16 base (92 us) + REGISTER-PRESSURE CUT: __launch_bounds__(256,4) caps the
// unified file at 128 regs/wave (R16 ran ~170 -> only 12 waves/CU resident;
// TLP was the binding constraint per issue-accounting: 36% VALUBusy at 3
// waves/SIMD with ~5100cy intervals vs ~600cy issue). Biases moved from 12
// pinned VGPRs to a 768B LDS table (broadcast reads, conflict-free) to give
// the allocator room. Pinned set now 44 regs. Skew structure unchanged:
// interval s = {L0(s), L1(s-1), L2(s-2)}, 16 lgkm-only barriers. Parity:
// reads at s hit (s+1)&1, writes s&1; h_l(init) at (l+1)&1. Frag maps
// (R3+ HW-verified): A row=c, k=32f+8g+j; B col=c, same k; D col=c, row=4g+r.
// Repack: kg=2mt+(g>>1), e=4(g&1)+r.
__global__ __launch_bounds__(256, 4) void rnn_mfma(
    const float* __restrict__ x,     // [B, T, 24]
    const float* __restrict__ h0in,  // [3, B, 64]
    const float* __restrict__ pWi0, const float* __restrict__ pWh0,
    const float* __restrict__ pbi0, const float* __restrict__ pbh0,
    const float* __restrict__ pWi1, const float* __restrict__ pWh1,
    const float* __restrict__ pbi1, const float* __restrict__ pbh1,
    const float* __restrict__ pWi2, const float* __restrict__ pWh2,
    const float* __restrict__ pbi2, const float* __restrict__ pbh2,
    const float* __restrict__ pWout, const float* __restrict__ pbout,
    float* __restrict__ out)         // [B*10] ++ [3*B*64]
{
    __shared__ __align__(16) short hbuf[2][3][8][NB][8];  // 24 KB
    __shared__ float blds[3][H];                          // scaled biases, 768B

    const int tid  = threadIdx.x;
    const int lane = tid & 63;
    const int g    = lane >> 4;      // k-group 0..3
    const int c    = lane & 15;      // col-in-n-tile / A-row-in-tile
    const int mt   = tid >> 6;       // wave id = m-tile 0..3
    const int b0   = blockIdx.x * NB;

    // ---- preload h_l(init) -> hbuf[(l+1)&1][l] (bf16); biases -> blds ----
    {
        const int b = tid & 31, k8 = (tid >> 5) & 7;
#pragma unroll
        for (int l = 0; l < 3; ++l) {
            const float* p = h0in + ((size_t)l * NBATCH + (b0 + b)) * H + k8 * 8;
            *(bf16x8*)&hbuf[(l + 1) & 1][l][k8][b][0] =
                pack8(*(const f32x4*)p, *(const f32x4*)(p + 4));
        }
    }
    if (tid < 192) {
        const int l = tid >> 6, j = tid & 63;
        const float* bi = l == 0 ? pbi0 : l == 1 ? pbi1 : pbi2;
        const float* bh = l == 0 ? pbh0 : l == 1 ? pbh1 : pbh2;
        blds[l][j] = WSCALE * (bi[j] + bh[j]);
    }

    // ---- weight A-fragments (bf16, prescaled, pinned: 44 regs) ----
    const int ia = mt * 16 + c;
    bf16x8 aWi0;
    if (g < 3) aWi0 = loadw8s(pWi0 + ia * IN + g * 8, WSCALE);
    else {
#pragma unroll
        for (int j = 0; j < 8; ++j) aWi0[j] = 0;   // k = 24..31 zero pad
    }
    PIN(aWi0);
    bf16x8 aWh0[2], aWi1[2], aWh1[2], aWi2[2], aWh2[2];
#pragma unroll
    for (int kt = 0; kt < 2; ++kt) {
        aWh0[kt] = loadw8s(pWh0 + ia * H + kt * 32 + g * 8, WSCALE);  PIN(aWh0[kt]);
        aWi1[kt] = loadw8s(pWi1 + ia * H + kt * 32 + g * 8, WSCALE);  PIN(aWi1[kt]);
        aWh1[kt] = loadw8s(pWh1 + ia * H + kt * 32 + g * 8, WSCALE);  PIN(aWh1[kt]);
        aWi2[kt] = loadw8s(pWi2 + ia * H + kt * 32 + g * 8, WSCALE);  PIN(aWi2[kt]);
        aWh2[kt] = loadw8s(pWh2 + ia * H + kt * 32 + g * 8, WSCALE);  PIN(aWh2[kt]);
    }

    const int i0  = mt * 16 + g * 4;     // D-row base (bias table offset)
    const int kgw = mt * 2 + (g >> 1);   // repack write kg
    const int eb  = (g & 1) * 4;         // repack write elem base

    const float* xb0 = x + (size_t)(b0 + c) * (SEQ * IN) + g * 8;        // nt0
    const float* xb1 = x + (size_t)(b0 + 16 + c) * (SEQ * IN) + g * 8;   // nt1
    float* hsout = out + (size_t)NBATCH * CLS;

    __syncthreads();   // initial full barrier (preload visibility)

// ---- layer-step macros; s_ determines parities: read (s_+1)&1, write s_&1.
// Bias read per section: lanes sharing (mt,g) read the same 16B -> broadcast.
#define L0S(s_)                                                                 \
    {                                                                           \
        const int pr = ((s_) + 1) & 1, pw = (s_) & 1, t = (s_);                 \
        bf16x8 bx0, bx1;                                                        \
        _Pragma("unroll")                                                       \
        for (int j = 0; j < 8; ++j) { bx0[j] = 0; bx1[j] = 0; }                 \
        if (g < 3) {                                                            \
            const float* p0 = xb0 + t * IN;                                     \
            const float* p1 = xb1 + t * IN;                                     \
            bx0 = pack8(*(const f32x4*)p0, *(const f32x4*)(p0 + 4));            \
            bx1 = pack8(*(const f32x4*)p1, *(const f32x4*)(p1 + 4));            \
        }                                                                       \
        f32x4 bsv = *(const f32x4*)&blds[0][i0];                                \
        bf16x8 s0a = *(const bf16x8*)&hbuf[pr][0][g][c][0];                     \
        bf16x8 s0b = *(const bf16x8*)&hbuf[pr][0][g][c + 16][0];                \
        bf16x8 s1a = *(const bf16x8*)&hbuf[pr][0][4 + g][c][0];                 \
        bf16x8 s1b = *(const bf16x8*)&hbuf[pr][0][4 + g][c + 16][0];            \
        f32x4 a0 = bsv, a1 = bsv;                                               \
        a0 = MFMA(aWh0[0], s0a, a0);  a1 = MFMA(aWh0[0], s0b, a1);              \
        a0 = MFMA(aWh0[1], s1a, a0);  a1 = MFMA(aWh0[1], s1b, a1);              \
        a0 = MFMA(aWi0,    bx0, a0);  a1 = MFMA(aWi0,    bx1, a1);              \
        f32x4 t0, t1;                                                           \
        _Pragma("unroll")                                                       \
        for (int r = 0; r < 4; ++r) { t0[r] = tanh2(a0[r]); t1[r] = tanh2(a1[r]); } \
        if (t == SEQ - 1) {                                                     \
            *(f32x4*)(hsout + (size_t)(b0 + c) * H + i0) = t0;                  \
            *(f32x4*)(hsout + (size_t)(b0 + 16 + c) * H + i0) = t1;             \
        }                                                                       \
        bf16x4 p0v, p1v;                                                        \
        _Pragma("unroll")                                                       \
        for (int r = 0; r < 4; ++r) { p0v[r] = f2bf(t0[r]); p1v[r] = f2bf(t1[r]); } \
        *(bf16x4*)&hbuf[pw][0][kgw][c][eb] = p0v;                               \
        *(bf16x4*)&hbuf[pw][0][kgw][c + 16][eb] = p1v;                          \
    }

#define L12S(s_, li, aWhX, aWiX)                                                \
    {                                                                           \
        const int pr = ((s_) + 1) & 1, pw = (s_) & 1, t = (s_) - (li);          \
        f32x4 bsv = *(const f32x4*)&blds[li][i0];                               \
        bf16x8 s0a = *(const bf16x8*)&hbuf[pr][li][g][c][0];                    \
        bf16x8 s0b = *(const bf16x8*)&hbuf[pr][li][g][c + 16][0];               \
        bf16x8 s1a = *(const bf16x8*)&hbuf[pr][li][4 + g][c][0];                \
        bf16x8 s1b = *(const bf16x8*)&hbuf[pr][li][4 + g][c + 16][0];           \
        bf16x8 b0a = *(const bf16x8*)&hbuf[pr][li - 1][g][c][0];                \
        bf16x8 b0b = *(const bf16x8*)&hbuf[pr][li - 1][g][c + 16][0];           \
        bf16x8 b1a = *(const bf16x8*)&hbuf[pr][li - 1][4 + g][c][0];            \
        bf16x8 b1b = *(const bf16x8*)&hbuf[pr][li - 1][4 + g][c + 16][0];       \
        f32x4 a0 = bsv, a1 = bsv;                                               \
        a0 = MFMA(aWhX[0], s0a, a0);  a1 = MFMA(aWhX[0], s0b, a1);              \
        a0 = MFMA(aWhX[1], s1a, a0);  a1 = MFMA(aWhX[1], s1b, a1);              \
        a0 = MFMA(aWiX[0], b0a, a0);  a1 = MFMA(aWiX[0], b0b, a1);              \
        a0 = MFMA(aWiX[1], b1a, a0);  a1 = MFMA(aWiX[1], b1b, a1);              \
        f32x4 t0, t1;                                                           \
        _Pragma("unroll")                                                       \
        for (int r = 0; r < 4; ++r) { t0[r] = tanh2(a0[r]); t1[r] = tanh2(a1[r]); } \
        if (t == SEQ - 1) {                                                     \
            float* hp = hsout + (size_t)(li) * NBATCH * H;                      \
            *(f32x4*)(hp + (size_t)(b0 + c) * H + i0) = t0;                     \
            *(f32x4*)(hp + (size_t)(b0 + 16 + c) * H + i0) = t1;                \
        }                                                                       \
        bf16x4 p0v, p1v;                                                        \
        _Pragma("unroll")                                                       \
        for (int r = 0; r < 4; ++r) { p0v[r] = f2bf(t0[r]); p1v[r] = f2bf(t1[r]); } \
        *(bf16x4*)&hbuf[pw][li][kgw][c][eb] = p0v;                              \
        *(bf16x4*)&hbuf[pw][li][kgw][c + 16][eb] = p1v;                         \
    }

    // ---- prologue: s=0, s=1 ----
    L0S(0);
    BAR();
    L0S(1);
    L12S(1, 1, aWh1, aWi1);
    BAR();

    // ---- main loop: s=2..SEQ-1 (straight-line 3-layer body, 1 barrier) ----
#pragma unroll 1
    for (int s = 2; s < SEQ; ++s) {
        L0S(s);
        L12S(s, 1, aWh1, aWi1);
        L12S(s, 2, aWh2, aWi2);
        BAR();
    }

    // ---- epilogue: s=SEQ (14), s=SEQ+1 (15) ----
    L12S(SEQ, 1, aWh1, aWi1);
    L12S(SEQ, 2, aWh2, aWi2);
    BAR();
    L12S(SEQ + 1, 2, aWh2, aWi2);
    BAR();

#undef L0S
#undef L12S

    // ===== logits head (MFMA, waves 0-1). Final h2 in parity (SEQ+1)&1 = 1.
    if (mt < 2) {
        bf16x8 aWo0, aWo1;
#pragma unroll
        for (int j = 0; j < 8; ++j) { aWo0[j] = 0; aWo1[j] = 0; }
        if (c < CLS) {
            aWo0 = loadw8(pWout + c * H + 8 * g);         // unscaled: no tanh
            aWo1 = loadw8(pWout + c * H + 32 + 8 * g);
        }
        const int col = c + 16 * mt;
        bf16x8 s0 = *(const bf16x8*)&hbuf[1][2][g][col][0];
        bf16x8 s1 = *(const bf16x8*)&hbuf[1][2][4 + g][col][0];
        f32x4 acc = {0.f, 0.f, 0.f, 0.f};
        acc = MFMA(aWo0, s0, acc);
        acc = MFMA(aWo1, s1, acc);
#pragma unroll
        for (int r = 0; r < 4; ++r) {
            const int cls = 4 * g + r;
            if (cls < CLS)
                out[(size_t)(b0 + col) * CLS + cls] = acc[r] + pbout[cls];
        }
    }
}

extern "C" void kernel_launch(void* const* d_in, const int* in_sizes, int n_in,
                              void* d_out, int out_size, void* d_ws, size_t ws_size,
                              hipStream_t stream) {
    const float* x    = (const float*)d_in[0];
    const float* h0in = (const float*)d_in[1];
    const float* Wi0  = (const float*)d_in[2];
    const float* Wh0  = (const float*)d_in[3];
    const float* bi0  = (const float*)d_in[4];
    const float* bh0  = (const float*)d_in[5];
    const float* Wi1  = (const float*)d_in[6];
    const float* Wh1  = (const float*)d_in[7];
    const float* bi1  = (const float*)d_in[8];
    const float* bh1  = (const float*)d_in[9];
    const float* Wi2  = (const float*)d_in[10];
    const float* Wh2  = (const float*)d_in[11];
    const float* bi2  = (const float*)d_in[12];
    const float* bh2  = (const float*)d_in[13];
    const float* Wout = (const float*)d_in[14];
    const float* bout = (const float*)d_in[15];
    float* out = (float*)d_out;

    dim3 grid(NBATCH / NB), block(256);
    rnn_mfma<<<grid, block, 0, stream>>>(x, h0in, Wi0, Wh0, bi0, bh0,
                                         Wi1, Wh1, bi1, bh1,
                                         Wi2, Wh2, bi2, bh2,
                                         Wout, bout, out);
}

// Round 18
// 90.923 us; speedup vs baseline: 1.0221x; 1.0221x over previous
//
#include <hip/hip_runtime.h>
#include <hip/hip_bf16.h>

#define SEQ 14
#define IN 24
#define H 64
#define CLS 10
#define NBATCH 65536
#define NB 32   // batch elems per block (best measured geometry)
// 2*log2(e): folds tanh's 2*v AND exp->exp2 into the f32 weight/bias prescale.
#define WSCALE 2.8853900817779268f

typedef __attribute__((ext_vector_type(4))) float f32x4;
typedef __attribute__((ext_vector_type(8))) short bf16x8;
typedef __attribute__((ext_vector_type(4))) short bf16x4;

#define MFMA(A, B, C) __builtin_amdgcn_mfma_f32_16x16x32_bf16(A, B, C, 0, 0, 0)
// Anti-rematerialization pin (R5-verified).
#define PIN(v) asm volatile("" : "+v"(v))
// Interval barrier: lgkmcnt(0) only (R15/R16-verified safe).
#define BAR()                                                \
    do {                                                     \
        asm volatile("s_waitcnt lgkmcnt(0)" ::: "memory");   \
        __builtin_amdgcn_s_barrier();                        \
    } while (0)

static __device__ __forceinline__ float fexp2(float x) {
#if __has_builtin(__builtin_amdgcn_exp2f)
    return __builtin_amdgcn_exp2f(x);   // v_exp_f32 (2^x)
#else
    return __expf(x * 0.6931471805599453f);
#endif
}
// y = 2*v*log2(e) (prescaled weights): tanh(v) = 1 - 2/(2^y + 1)
static __device__ __forceinline__ float tanh2(float y) {
    float e = fexp2(y);
    return fmaf(-2.0f, __builtin_amdgcn_rcpf(e + 1.0f), 1.0f);
}
static __device__ __forceinline__ short f2bf(float f) {
    __hip_bfloat16 h = __float2bfloat16(f);
    union { __hip_bfloat16 h; short s; } u; u.h = h;
    return u.s;
}
static __device__ __forceinline__ bf16x8 pack8(f32x4 a, f32x4 b) {
    bf16x8 r;
    r[0] = f2bf(a[0]); r[1] = f2bf(a[1]); r[2] = f2bf(a[2]); r[3] = f2bf(a[3]);
    r[4] = f2bf(b[0]); r[5] = f2bf(b[1]); r[6] = f2bf(b[2]); r[7] = f2bf(b[3]);
    return r;
}
static __device__ __forceinline__ bf16x8 loadw8(const float* p) {
    return pack8(*(const f32x4*)p, *(const f32x4*)(p + 4));
}
static __device__ __forceinline__ bf16x8 loadw8s(const float* p, float s) {
    f32x4 a = *(const f32x4*)p, b = *(const f32x4*)(p + 4);
    return pack8(a * s, b * s);
}

// R16 base (92.3 us) + OPERAND-REGISTER REUSE: within interval s, hbuf[pr][0]
// is needed by BOTH L0 (self: h0(s-1)) and L1 (below: h0(s-1)) -- same parity,
// same addresses; likewise hbuf[pr][1] by L1 (self) and L2 (below). Read each
// tile ONCE into named frags (r0/r1/r2) and share: 20 -> 12 ds_read_b128 per
// wave-interval (-40% LDS reads, ~20 us chip-wide LDS-pipe time).
// Skew structure unchanged: interval s = {L0(s), L1(s-1), L2(s-2)}, 16
// lgkm-only barriers. Parity: reads at s hit (s+1)&1, writes s&1; h_l(init)
// at (l+1)&1. Frag maps (R3+ HW-verified): A row=c, k=32f+8g+j; B col=c,
// same k; D col=c, row=4g+r. Repack: kg=2mt+(g>>1), e=4(g&1)+r.
__global__ __launch_bounds__(256, 2) void rnn_mfma(
    const float* __restrict__ x,     // [B, T, 24]
    const float* __restrict__ h0in,  // [3, B, 64]
    const float* __restrict__ pWi0, const float* __restrict__ pWh0,
    const float* __restrict__ pbi0, const float* __restrict__ pbh0,
    const float* __restrict__ pWi1, const float* __restrict__ pWh1,
    const float* __restrict__ pbi1, const float* __restrict__ pbh1,
    const float* __restrict__ pWi2, const float* __restrict__ pWh2,
    const float* __restrict__ pbi2, const float* __restrict__ pbh2,
    const float* __restrict__ pWout, const float* __restrict__ pbout,
    float* __restrict__ out)         // [B*10] ++ [3*B*64]
{
    __shared__ __align__(16) short hbuf[2][3][8][NB][8];  // 24 KB

    const int tid  = threadIdx.x;
    const int lane = tid & 63;
    const int g    = lane >> 4;      // k-group 0..3
    const int c    = lane & 15;      // col-in-n-tile / A-row-in-tile
    const int mt   = tid >> 6;       // wave id = m-tile 0..3
    const int b0   = blockIdx.x * NB;

    // ---- preload h_l(init) -> hbuf[(l+1)&1][l] (bf16) ----
    {
        const int b = tid & 31, k8 = (tid >> 5) & 7;
#pragma unroll
        for (int l = 0; l < 3; ++l) {
            const float* p = h0in + ((size_t)l * NBATCH + (b0 + b)) * H + k8 * 8;
            *(bf16x8*)&hbuf[(l + 1) & 1][l][k8][b][0] =
                pack8(*(const f32x4*)p, *(const f32x4*)(p + 4));
        }
    }

    // ---- weight A-fragments (bf16, prescaled, pinned) ----
    const int ia = mt * 16 + c;
    bf16x8 aWi0;
    if (g < 3) aWi0 = loadw8s(pWi0 + ia * IN + g * 8, WSCALE);
    else {
#pragma unroll
        for (int j = 0; j < 8; ++j) aWi0[j] = 0;   // k = 24..31 zero pad
    }
    PIN(aWi0);
    bf16x8 aWh0[2], aWi1[2], aWh1[2], aWi2[2], aWh2[2];
#pragma unroll
    for (int kt = 0; kt < 2; ++kt) {
        aWh0[kt] = loadw8s(pWh0 + ia * H + kt * 32 + g * 8, WSCALE);  PIN(aWh0[kt]);
        aWi1[kt] = loadw8s(pWi1 + ia * H + kt * 32 + g * 8, WSCALE);  PIN(aWi1[kt]);
        aWh1[kt] = loadw8s(pWh1 + ia * H + kt * 32 + g * 8, WSCALE);  PIN(aWh1[kt]);
        aWi2[kt] = loadw8s(pWi2 + ia * H + kt * 32 + g * 8, WSCALE);  PIN(aWi2[kt]);
        aWh2[kt] = loadw8s(pWh2 + ia * H + kt * 32 + g * 8, WSCALE);  PIN(aWh2[kt]);
    }

    // ---- scaled bias acc-init vectors, pinned ----
    const int i0 = mt * 16 + g * 4;
    f32x4 bs0 = (*(const f32x4*)(pbi0 + i0) + *(const f32x4*)(pbh0 + i0)) * WSCALE;
    f32x4 bs1 = (*(const f32x4*)(pbi1 + i0) + *(const f32x4*)(pbh1 + i0)) * WSCALE;
    f32x4 bs2 = (*(const f32x4*)(pbi2 + i0) + *(const f32x4*)(pbh2 + i0)) * WSCALE;
    PIN(bs0); PIN(bs1); PIN(bs2);

    const int kgw = mt * 2 + (g >> 1);   // repack write kg
    const int eb  = (g & 1) * 4;         // repack write elem base

    const float* xb0 = x + (size_t)(b0 + c) * (SEQ * IN) + g * 8;        // nt0
    const float* xb1 = x + (size_t)(b0 + 16 + c) * (SEQ * IN) + g * 8;   // nt1
    float* hsout = out + (size_t)NBATCH * CLS;

    __syncthreads();   // initial full barrier (preload visibility)

// ---- read one layer-tile of parity pr_ into frags pfx{0a,0b,1a,1b} ----
#define RDF(pfx, pr_, li)                                                       \
    bf16x8 pfx##0a = *(const bf16x8*)&hbuf[pr_][li][g][c][0];                   \
    bf16x8 pfx##0b = *(const bf16x8*)&hbuf[pr_][li][g][c + 16][0];              \
    bf16x8 pfx##1a = *(const bf16x8*)&hbuf[pr_][li][4 + g][c][0];               \
    bf16x8 pfx##1b = *(const bf16x8*)&hbuf[pr_][li][4 + g][c + 16][0];

// ---- L0 section: self = P frags (h0(s-1)); writes h0(s) to parity s&1 ----
#define L0B(s_, P)                                                              \
    {                                                                           \
        const int pw = (s_) & 1, t = (s_);                                      \
        bf16x8 bx0, bx1;                                                        \
        _Pragma("unroll")                                                       \
        for (int j = 0; j < 8; ++j) { bx0[j] = 0; bx1[j] = 0; }                 \
        if (g < 3) {                                                            \
            const float* p0 = xb0 + t * IN;                                     \
            const float* p1 = xb1 + t * IN;                                     \
            bx0 = pack8(*(const f32x4*)p0, *(const f32x4*)(p0 + 4));            \
            bx1 = pack8(*(const f32x4*)p1, *(const f32x4*)(p1 + 4));            \
        }                                                                       \
        f32x4 a0 = bs0, a1 = bs0;                                               \
        a0 = MFMA(aWh0[0], P##0a, a0);  a1 = MFMA(aWh0[0], P##0b, a1);          \
        a0 = MFMA(aWh0[1], P##1a, a0);  a1 = MFMA(aWh0[1], P##1b, a1);          \
        a0 = MFMA(aWi0,    bx0,   a0);  a1 = MFMA(aWi0,    bx1,   a1);          \
        f32x4 t0, t1;                                                           \
        _Pragma("unroll")                                                       \
        for (int r = 0; r < 4; ++r) { t0[r] = tanh2(a0[r]); t1[r] = tanh2(a1[r]); } \
        if (t == SEQ - 1) {                                                     \
            *(f32x4*)(hsout + (size_t)(b0 + c) * H + i0) = t0;                  \
            *(f32x4*)(hsout + (size_t)(b0 + 16 + c) * H + i0) = t1;             \
        }                                                                       \
        bf16x4 p0v, p1v;                                                        \
        _Pragma("unroll")                                                       \
        for (int r = 0; r < 4; ++r) { p0v[r] = f2bf(t0[r]); p1v[r] = f2bf(t1[r]); } \
        *(bf16x4*)&hbuf[pw][0][kgw][c][eb] = p0v;                               \
        *(bf16x4*)&hbuf[pw][0][kgw][c + 16][eb] = p1v;                          \
    }

// ---- L1/L2 section: self = S frags, below = B frags (shared with prior) ----
#define L12B(s_, li, bsv, S, B, aWhX, aWiX)                                     \
    {                                                                           \
        const int pw = (s_) & 1, t = (s_) - (li);                               \
        f32x4 a0 = bsv, a1 = bsv;                                               \
        a0 = MFMA(aWhX[0], S##0a, a0);  a1 = MFMA(aWhX[0], S##0b, a1);          \
        a0 = MFMA(aWhX[1], S##1a, a0);  a1 = MFMA(aWhX[1], S##1b, a1);          \
        a0 = MFMA(aWiX[0], B##0a, a0);  a1 = MFMA(aWiX[0], B##0b, a1);          \
        a0 = MFMA(aWiX[1], B##1a, a0);  a1 = MFMA(aWiX[1], B##1b, a1);          \
        f32x4 t0, t1;                                                           \
        _Pragma("unroll")                                                       \
        for (int r = 0; r < 4; ++r) { t0[r] = tanh2(a0[r]); t1[r] = tanh2(a1[r]); } \
        if (t == SEQ - 1) {                                                     \
            float* hp = hsout + (size_t)(li) * NBATCH * H;                      \
            *(f32x4*)(hp + (size_t)(b0 + c) * H + i0) = t0;                     \
            *(f32x4*)(hp + (size_t)(b0 + 16 + c) * H + i0) = t1;                \
        }                                                                       \
        bf16x4 p0v, p1v;                                                        \
        _Pragma("unroll")                                                       \
        for (int r = 0; r < 4; ++r) { p0v[r] = f2bf(t0[r]); p1v[r] = f2bf(t1[r]); } \
        *(bf16x4*)&hbuf[pw][li][kgw][c][eb] = p0v;                              \
        *(bf16x4*)&hbuf[pw][li][kgw][c + 16][eb] = p1v;                         \
    }

    // ---- prologue: s=0 (h0 init at parity 1), s=1 ----
    {
        RDF(r0, 1, 0)
        L0B(0, r0)
    }
    BAR();
    {
        RDF(r0, 0, 0)          // h0(t=0), also L1's below
        L0B(1, r0)
        RDF(r1, 0, 1)          // h1 init at parity (1+1)&1 = 0
        L12B(1, 1, bs1, r1, r0, aWh1, aWi1)
    }
    BAR();

    // ---- main loop: s=2..SEQ-1; each tile read ONCE, shared ----
#pragma unroll 1
    for (int s = 2; s < SEQ; ++s) {
        const int pr = (s + 1) & 1;
        RDF(r0, pr, 0)         // h0(s-1): L0 self + L1 below
        L0B(s, r0)
        RDF(r1, pr, 1)         // h1(s-2): L1 self + L2 below
        L12B(s, 1, bs1, r1, r0, aWh1, aWi1)
        RDF(r2, pr, 2)         // h2(s-3): L2 self
        L12B(s, 2, bs2, r2, r1, aWh2, aWi2)
        BAR();
    }

    // ---- epilogue: s=14 (L1,L2), s=15 (L2) ----
    {
        RDF(r0, 1, 0)          // h0(t=13)
        RDF(r1, 1, 1)          // h1(t=12)
        L12B(SEQ, 1, bs1, r1, r0, aWh1, aWi1)
        RDF(r2, 1, 2)          // h2(t=11)
        L12B(SEQ, 2, bs2, r2, r1, aWh2, aWi2)
    }
    BAR();
    {
        RDF(r1, 0, 1)          // h1(t=13)
        RDF(r2, 0, 2)          // h2(t=12)
        L12B(SEQ + 1, 2, bs2, r2, r1, aWh2, aWi2)
    }
    BAR();

#undef RDF
#undef L0B
#undef L12B

    // ===== logits head (MFMA, waves 0-1). Final h2 in parity (SEQ+1)&1 = 1.
    if (mt < 2) {
        bf16x8 aWo0, aWo1;
#pragma unroll
        for (int j = 0; j < 8; ++j) { aWo0[j] = 0; aWo1[j] = 0; }
        if (c < CLS) {
            aWo0 = loadw8(pWout + c * H + 8 * g);         // unscaled: no tanh
            aWo1 = loadw8(pWout + c * H + 32 + 8 * g);
        }
        const int col = c + 16 * mt;
        bf16x8 s0 = *(const bf16x8*)&hbuf[1][2][g][col][0];
        bf16x8 s1 = *(const bf16x8*)&hbuf[1][2][4 + g][col][0];
        f32x4 acc = {0.f, 0.f, 0.f, 0.f};
        acc = MFMA(aWo0, s0, acc);
        acc = MFMA(aWo1, s1, acc);
#pragma unroll
        for (int r = 0; r < 4; ++r) {
            const int cls = 4 * g + r;
            if (cls < CLS)
                out[(size_t)(b0 + col) * CLS + cls] = acc[r] + pbout[cls];
        }
    }
}

extern "C" void kernel_launch(void* const* d_in, const int* in_sizes, int n_in,
                              void* d_out, int out_size, void* d_ws, size_t ws_size,
                              hipStream_t stream) {
    const float* x    = (const float*)d_in[0];
    const float* h0in = (const float*)d_in[1];
    const float* Wi0  = (const float*)d_in[2];
    const float* Wh0  = (const float*)d_in[3];
    const float* bi0  = (const float*)d_in[4];
    const float* bh0  = (const float*)d_in[5];
    const float* Wi1  = (const float*)d_in[6];
    const float* Wh1  = (const float*)d_in[7];
    const float* bi1  = (const float*)d_in[8];
    const float* bh1  = (const float*)d_in[9];
    const float* Wi2  = (const float*)d_in[10];
    const float* Wh2  = (const float*)d_in[11];
    const float* bi2  = (const float*)d_in[12];
    const float* bh2  = (const float*)d_in[13];
    const float* Wout = (const float*)d_in[14];
    const float* bout = (const float*)d_in[15];
    float* out = (float*)d_out;

    dim3 grid(NBATCH / NB), block(256);
    rnn_mfma<<<grid, block, 0, stream>>>(x, h0in, Wi0, Wh0, bi0, bh0,
                                         Wi1, Wh1, bi1, bh1,
                                         Wi2, Wh2, bi2, bh2,
                                         Wout, bout, out);
}

// Round 19
// 88.261 us; speedup vs baseline: 1.0529x; 1.0302x over previous
//
#include <hip/hip_runtime.h>
#include <hip/hip_bf16.h>

#define SEQ 14
#define IN 24
#define H 64
#define CLS 10
#define NBATCH 65536
#define NB 32   // batch elems per block (best measured geometry)
// 2*log2(e): folds tanh's 2*v AND exp->exp2 into the f32 weight/bias prescale.
#define WSCALE 2.8853900817779268f

typedef __attribute__((ext_vector_type(4))) float f32x4;
typedef __attribute__((ext_vector_type(8))) short bf16x8;
typedef __attribute__((ext_vector_type(4))) short bf16x4;

#define MFMA(A, B, C) __builtin_amdgcn_mfma_f32_16x16x32_bf16(A, B, C, 0, 0, 0)
// Anti-rematerialization pin (R5-verified).
#define PIN(v) asm volatile("" : "+v"(v))
// Interval barrier: lgkmcnt(0) only (R15/R16-verified safe).
#define BAR()                                                \
    do {                                                     \
        asm volatile("s_waitcnt lgkmcnt(0)" ::: "memory");   \
        __builtin_amdgcn_s_barrier();                        \
    } while (0)

static __device__ __forceinline__ float fexp2(float x) {
#if __has_builtin(__builtin_amdgcn_exp2f)
    return __builtin_amdgcn_exp2f(x);   // v_exp_f32 (2^x)
#else
    return __expf(x * 0.6931471805599453f);
#endif
}
// y = 2*v*log2(e) (prescaled weights): tanh(v) = 1 - 2/(2^y + 1)
static __device__ __forceinline__ float tanh2(float y) {
    float e = fexp2(y);
    return fmaf(-2.0f, __builtin_amdgcn_rcpf(e + 1.0f), 1.0f);
}
static __device__ __forceinline__ short f2bf(float f) {
    __hip_bfloat16 h = __float2bfloat16(f);
    union { __hip_bfloat16 h; short s; } u; u.h = h;
    return u.s;
}
static __device__ __forceinline__ bf16x8 pack8(f32x4 a, f32x4 b) {
    bf16x8 r;
    r[0] = f2bf(a[0]); r[1] = f2bf(a[1]); r[2] = f2bf(a[2]); r[3] = f2bf(a[3]);
    r[4] = f2bf(b[0]); r[5] = f2bf(b[1]); r[6] = f2bf(b[2]); r[7] = f2bf(b[3]);
    return r;
}
static __device__ __forceinline__ bf16x8 loadw8(const float* p) {
    return pack8(*(const f32x4*)p, *(const f32x4*)(p + 4));
}
static __device__ __forceinline__ bf16x8 loadw8s(const float* p, float s) {
    f32x4 a = *(const f32x4*)p, b = *(const f32x4*)(p + 4);
    return pack8(a * s, b * s);
}

// R18 base (90.9 us) + X STAGED IN LDS: all 14 timesteps of this block's x
// pre-converted to bf16 in B-frag layout xlds[t][kg][col][8] (kg3 = zeros so
// L0 is branchless). Removes the per-interval global x load (~200-500cy
// vmcnt stall, the only global latency left in the t-loop) and 8 cvt_pk per
// wave-interval, at ZERO register cost (the lesson from R12/R15: register
// prefetch of x costs more residency than it hides). LDS 53.2KB -> still
// 3 blocks/CU (residency unchanged).
// Skew structure unchanged: interval s = {L0(s), L1(s-1), L2(s-2)}, 16
// lgkm-only barriers; operand-register reuse across sections (R18). Parity:
// reads at s hit (s+1)&1, writes s&1; h_l(init) at (l+1)&1. Frag maps
// (R3+ HW-verified): A row=c, k=32f+8g+j; B col=c, same k; D col=c, row=4g+r.
// Repack: kg=2mt+(g>>1), e=4(g&1)+r.
__global__ __launch_bounds__(256, 2) void rnn_mfma(
    const float* __restrict__ x,     // [B, T, 24]
    const float* __restrict__ h0in,  // [3, B, 64]
    const float* __restrict__ pWi0, const float* __restrict__ pWh0,
    const float* __restrict__ pbi0, const float* __restrict__ pbh0,
    const float* __restrict__ pWi1, const float* __restrict__ pWh1,
    const float* __restrict__ pbi1, const float* __restrict__ pbh1,
    const float* __restrict__ pWi2, const float* __restrict__ pWh2,
    const float* __restrict__ pbi2, const float* __restrict__ pbh2,
    const float* __restrict__ pWout, const float* __restrict__ pbout,
    float* __restrict__ out)         // [B*10] ++ [3*B*64]
{
    __shared__ __align__(16) short hbuf[2][3][8][NB][8];   // 24.0 KB
    __shared__ __align__(16) short xlds[SEQ][4][NB][8];    // 28.0 KB (kg3 = 0)

    const int tid  = threadIdx.x;
    const int lane = tid & 63;
    const int g    = lane >> 4;      // k-group 0..3
    const int c    = lane & 15;      // col-in-n-tile / A-row-in-tile
    const int mt   = tid >> 6;       // wave id = m-tile 0..3
    const int b0   = blockIdx.x * NB;

    // ---- preload h_l(init) -> hbuf[(l+1)&1][l] (bf16) ----
    {
        const int b = tid & 31, k8 = (tid >> 5) & 7;
#pragma unroll
        for (int l = 0; l < 3; ++l) {
            const float* p = h0in + ((size_t)l * NBATCH + (b0 + b)) * H + k8 * 8;
            *(bf16x8*)&hbuf[(l + 1) & 1][l][k8][b][0] =
                pack8(*(const f32x4*)p, *(const f32x4*)(p + 4));
        }
    }
    // ---- stage x -> xlds (bf16, B-layout); kg3 zero-filled ----
    {
        bf16x8 z;
#pragma unroll
        for (int j = 0; j < 8; ++j) z[j] = 0;
        for (int i = tid; i < SEQ * NB; i += 256) {
            const int t = i >> 5, col = i & 31;
            *(bf16x8*)&xlds[t][3][col][0] = z;
        }
        // 84 f32x4 chunks per col (14*24/4); each chunk stays within one kg.
        for (int i = tid; i < NB * 84; i += 256) {
            const int col = i / 84, ch = i - col * 84;
            const int o = ch * 4, t = o / 24, k = o - t * 24;
            f32x4 v = *(const f32x4*)(x + (size_t)(b0 + col) * (SEQ * IN) + o);
            bf16x4 pv;
#pragma unroll
            for (int r = 0; r < 4; ++r) pv[r] = f2bf(v[r]);
            *(bf16x4*)&xlds[t][k >> 3][col][k & 7] = pv;
        }
    }

    // ---- weight A-fragments (bf16, prescaled, pinned) ----
    const int ia = mt * 16 + c;
    bf16x8 aWi0;
    if (g < 3) aWi0 = loadw8s(pWi0 + ia * IN + g * 8, WSCALE);
    else {
#pragma unroll
        for (int j = 0; j < 8; ++j) aWi0[j] = 0;   // k = 24..31 zero pad
    }
    PIN(aWi0);
    bf16x8 aWh0[2], aWi1[2], aWh1[2], aWi2[2], aWh2[2];
#pragma unroll
    for (int kt = 0; kt < 2; ++kt) {
        aWh0[kt] = loadw8s(pWh0 + ia * H + kt * 32 + g * 8, WSCALE);  PIN(aWh0[kt]);
        aWi1[kt] = loadw8s(pWi1 + ia * H + kt * 32 + g * 8, WSCALE);  PIN(aWi1[kt]);
        aWh1[kt] = loadw8s(pWh1 + ia * H + kt * 32 + g * 8, WSCALE);  PIN(aWh1[kt]);
        aWi2[kt] = loadw8s(pWi2 + ia * H + kt * 32 + g * 8, WSCALE);  PIN(aWi2[kt]);
        aWh2[kt] = loadw8s(pWh2 + ia * H + kt * 32 + g * 8, WSCALE);  PIN(aWh2[kt]);
    }

    // ---- scaled bias acc-init vectors, pinned ----
    const int i0 = mt * 16 + g * 4;
    f32x4 bs0 = (*(const f32x4*)(pbi0 + i0) + *(const f32x4*)(pbh0 + i0)) * WSCALE;
    f32x4 bs1 = (*(const f32x4*)(pbi1 + i0) + *(const f32x4*)(pbh1 + i0)) * WSCALE;
    f32x4 bs2 = (*(const f32x4*)(pbi2 + i0) + *(const f32x4*)(pbh2 + i0)) * WSCALE;
    PIN(bs0); PIN(bs1); PIN(bs2);

    const int kgw = mt * 2 + (g >> 1);   // repack write kg
    const int eb  = (g & 1) * 4;         // repack write elem base
    float* hsout = out + (size_t)NBATCH * CLS;

    __syncthreads();   // initial full barrier (preload + staging visibility)

// ---- read one layer-tile of parity pr_ into frags pfx{0a,0b,1a,1b} ----
#define RDF(pfx, pr_, li)                                                       \
    bf16x8 pfx##0a = *(const bf16x8*)&hbuf[pr_][li][g][c][0];                   \
    bf16x8 pfx##0b = *(const bf16x8*)&hbuf[pr_][li][g][c + 16][0];              \
    bf16x8 pfx##1a = *(const bf16x8*)&hbuf[pr_][li][4 + g][c][0];               \
    bf16x8 pfx##1b = *(const bf16x8*)&hbuf[pr_][li][4 + g][c + 16][0];

// ---- L0 section: self = P frags (h0(s-1)); x from xlds (branchless) ----
#define L0B(s_, P)                                                              \
    {                                                                           \
        const int pw = (s_) & 1, t = (s_);                                      \
        bf16x8 bx0 = *(const bf16x8*)&xlds[t][g][c][0];                         \
        bf16x8 bx1 = *(const bf16x8*)&xlds[t][g][c + 16][0];                    \
        f32x4 a0 = bs0, a1 = bs0;                                               \
        a0 = MFMA(aWh0[0], P##0a, a0);  a1 = MFMA(aWh0[0], P##0b, a1);          \
        a0 = MFMA(aWh0[1], P##1a, a0);  a1 = MFMA(aWh0[1], P##1b, a1);          \
        a0 = MFMA(aWi0,    bx0,   a0);  a1 = MFMA(aWi0,    bx1,   a1);          \
        f32x4 t0, t1;                                                           \
        _Pragma("unroll")                                                       \
        for (int r = 0; r < 4; ++r) { t0[r] = tanh2(a0[r]); t1[r] = tanh2(a1[r]); } \
        if (t == SEQ - 1) {                                                     \
            *(f32x4*)(hsout + (size_t)(b0 + c) * H + i0) = t0;                  \
            *(f32x4*)(hsout + (size_t)(b0 + 16 + c) * H + i0) = t1;             \
        }                                                                       \
        bf16x4 p0v, p1v;                                                        \
        _Pragma("unroll")                                                       \
        for (int r = 0; r < 4; ++r) { p0v[r] = f2bf(t0[r]); p1v[r] = f2bf(t1[r]); } \
        *(bf16x4*)&hbuf[pw][0][kgw][c][eb] = p0v;                               \
        *(bf16x4*)&hbuf[pw][0][kgw][c + 16][eb] = p1v;                          \
    }

// ---- L1/L2 section: self = S frags, below = B frags (shared with prior) ----
#define L12B(s_, li, bsv, S, B, aWhX, aWiX)                                     \
    {                                                                           \
        const int pw = (s_) & 1, t = (s_) - (li);                               \
        f32x4 a0 = bsv, a1 = bsv;                                               \
        a0 = MFMA(aWhX[0], S##0a, a0);  a1 = MFMA(aWhX[0], S##0b, a1);          \
        a0 = MFMA(aWhX[1], S##1a, a0);  a1 = MFMA(aWhX[1], S##1b, a1);          \
        a0 = MFMA(aWiX[0], B##0a, a0);  a1 = MFMA(aWiX[0], B##0b, a1);          \
        a0 = MFMA(aWiX[1], B##1a, a0);  a1 = MFMA(aWiX[1], B##1b, a1);          \
        f32x4 t0, t1;                                                           \
        _Pragma("unroll")                                                       \
        for (int r = 0; r < 4; ++r) { t0[r] = tanh2(a0[r]); t1[r] = tanh2(a1[r]); } \
        if (t == SEQ - 1) {                                                     \
            float* hp = hsout + (size_t)(li) * NBATCH * H;                      \
            *(f32x4*)(hp + (size_t)(b0 + c) * H + i0) = t0;                     \
            *(f32x4*)(hp + (size_t)(b0 + 16 + c) * H + i0) = t1;                \
        }                                                                       \
        bf16x4 p0v, p1v;                                                        \
        _Pragma("unroll")                                                       \
        for (int r = 0; r < 4; ++r) { p0v[r] = f2bf(t0[r]); p1v[r] = f2bf(t1[r]); } \
        *(bf16x4*)&hbuf[pw][li][kgw][c][eb] = p0v;                              \
        *(bf16x4*)&hbuf[pw][li][kgw][c + 16][eb] = p1v;                         \
    }

    // ---- prologue: s=0 (h0 init at parity 1), s=1 ----
    {
        RDF(r0, 1, 0)
        L0B(0, r0)
    }
    BAR();
    {
        RDF(r0, 0, 0)          // h0(t=0), also L1's below
        L0B(1, r0)
        RDF(r1, 0, 1)          // h1 init at parity (1+1)&1 = 0
        L12B(1, 1, bs1, r1, r0, aWh1, aWi1)
    }
    BAR();

    // ---- main loop: s=2..SEQ-1; each tile read ONCE, shared ----
#pragma unroll 1
    for (int s = 2; s < SEQ; ++s) {
        const int pr = (s + 1) & 1;
        RDF(r0, pr, 0)         // h0(s-1): L0 self + L1 below
        L0B(s, r0)
        RDF(r1, pr, 1)         // h1(s-2): L1 self + L2 below
        L12B(s, 1, bs1, r1, r0, aWh1, aWi1)
        RDF(r2, pr, 2)         // h2(s-3): L2 self
        L12B(s, 2, bs2, r2, r1, aWh2, aWi2)
        BAR();
    }

    // ---- epilogue: s=14 (L1,L2), s=15 (L2) ----
    {
        RDF(r0, 1, 0)          // h0(t=13)
        RDF(r1, 1, 1)          // h1(t=12)
        L12B(SEQ, 1, bs1, r1, r0, aWh1, aWi1)
        RDF(r2, 1, 2)          // h2(t=11)
        L12B(SEQ, 2, bs2, r2, r1, aWh2, aWi2)
    }
    BAR();
    {
        RDF(r1, 0, 1)          // h1(t=13)
        RDF(r2, 0, 2)          // h2(t=12)
        L12B(SEQ + 1, 2, bs2, r2, r1, aWh2, aWi2)
    }
    BAR();

#undef RDF
#undef L0B
#undef L12B

    // ===== logits head (MFMA, waves 0-1). Final h2 in parity (SEQ+1)&1 = 1.
    if (mt < 2) {
        bf16x8 aWo0, aWo1;
#pragma unroll
        for (int j = 0; j < 8; ++j) { aWo0[j] = 0; aWo1[j] = 0; }
        if (c < CLS) {
            aWo0 = loadw8(pWout + c * H + 8 * g);         // unscaled: no tanh
            aWo1 = loadw8(pWout + c * H + 32 + 8 * g);
        }
        const int col = c + 16 * mt;
        bf16x8 s0 = *(const bf16x8*)&hbuf[1][2][g][col][0];
        bf16x8 s1 = *(const bf16x8*)&hbuf[1][2][4 + g][col][0];
        f32x4 acc = {0.f, 0.f, 0.f, 0.f};
        acc = MFMA(aWo0, s0, acc);
        acc = MFMA(aWo1, s1, acc);
#pragma unroll
        for (int r = 0; r < 4; ++r) {
            const int cls = 4 * g + r;
            if (cls < CLS)
                out[(size_t)(b0 + col) * CLS + cls] = acc[r] + pbout[cls];
        }
    }
}

extern "C" void kernel_launch(void* const* d_in, const int* in_sizes, int n_in,
                              void* d_out, int out_size, void* d_ws, size_t ws_size,
                              hipStream_t stream) {
    const float* x    = (const float*)d_in[0];
    const float* h0in = (const float*)d_in[1];
    const float* Wi0  = (const float*)d_in[2];
    const float* Wh0  = (const float*)d_in[3];
    const float* bi0  = (const float*)d_in[4];
    const float* bh0  = (const float*)d_in[5];
    const float* Wi1  = (const float*)d_in[6];
    const float* Wh1  = (const float*)d_in[7];
    const float* bi1  = (const float*)d_in[8];
    const float* bh1  = (const float*)d_in[9];
    const float* Wi2  = (const float*)d_in[10];
    const float* Wh2  = (const float*)d_in[11];
    const float* bi2  = (const float*)d_in[12];
    const float* bh2  = (const float*)d_in[13];
    const float* Wout = (const float*)d_in[14];
    const float* bout = (const float*)d_in[15];
    float* out = (float*)d_out;

    dim3 grid(NBATCH / NB), block(256);
    rnn_mfma<<<grid, block, 0, stream>>>(x, h0in, Wi0, Wh0, bi0, bh0,
                                         Wi1, Wh1, bi1, bh1,
                                         Wi2, Wh2, bi2, bh2,
                                         Wout, bout, out);
}